// Round 3
// baseline (1075.277 us; speedup 1.0000x reference)
//
#include <hip/hip_runtime.h>
#include <stdint.h>

// native 4-float vector for nontemporal builtins (same layout as float4)
typedef float floatx4 __attribute__((ext_vector_type(4)));

// ---------------------------------------------------------------------------
// Host copy of exact JAX Threefry-2x32 (jax/_src/prng.py; Random123 constants)
// used only to derive rkey = fold_in(key(42), 0) on the host.
// ---------------------------------------------------------------------------
static inline void threefry2x32_host(uint32_t k0, uint32_t k1,
                                     uint32_t x0, uint32_t x1,
                                     uint32_t& o0, uint32_t& o1) {
  const uint32_t ks2 = k0 ^ k1 ^ 0x1BD11BDAu;
#define TF_ROUND(r) { x0 += x1; x1 = (x1 << (r)) | (x1 >> (32 - (r))); x1 ^= x0; }
  x0 += k0; x1 += k1;
  TF_ROUND(13) TF_ROUND(15) TF_ROUND(26) TF_ROUND(6)
  x0 += k1;  x1 += ks2 + 1u;
  TF_ROUND(17) TF_ROUND(29) TF_ROUND(16) TF_ROUND(24)
  x0 += ks2; x1 += k0 + 2u;
  TF_ROUND(13) TF_ROUND(15) TF_ROUND(26) TF_ROUND(6)
  x0 += k0;  x1 += k1 + 3u;
  TF_ROUND(17) TF_ROUND(29) TF_ROUND(16) TF_ROUND(24)
  x0 += k1;  x1 += ks2 + 4u;
  TF_ROUND(13) TF_ROUND(15) TF_ROUND(26) TF_ROUND(6)
  x0 += ks2; x1 += k0 + 5u;
#undef TF_ROUND
  o0 = x0; o1 = x1;
}

// ---------------------------------------------------------------------------
// Device: jax partitionable 32-bit draw for counter ctr (< 2^32).
// Caller passes x1 = ctr + k1 (initial key add strength-reduced); x0 = k0.
// Rotates via __builtin_rotateleft32 -> v_alignbit_b32.
// 20*(add,alignbit,xor) + 10 injection adds + final xor ~= 73 VALU ops.
// ---------------------------------------------------------------------------
__device__ __forceinline__ uint32_t tf_bits(uint32_t x1, uint32_t k0,
                                            uint32_t k1, uint32_t ks2) {
  uint32_t x0 = k0;
#define R4(a,b,c,d)                                              \
  x0 += x1; x1 = __builtin_rotateleft32(x1, a); x1 ^= x0;        \
  x0 += x1; x1 = __builtin_rotateleft32(x1, b); x1 ^= x0;        \
  x0 += x1; x1 = __builtin_rotateleft32(x1, c); x1 ^= x0;        \
  x0 += x1; x1 = __builtin_rotateleft32(x1, d); x1 ^= x0;
  R4(13, 15, 26, 6)
  x0 += k1;  x1 += ks2 + 1u;
  R4(17, 29, 16, 24)
  x0 += ks2; x1 += k0 + 2u;
  R4(13, 15, 26, 6)
  x0 += k0;  x1 += k1 + 3u;
  R4(17, 29, 16, 24)
  x0 += k1;  x1 += ks2 + 4u;
  R4(13, 15, 26, 6)
  x0 += ks2; x1 += k0 + 5u;
#undef R4
  return x0 ^ x1;  // bits = o0 ^ o1 (partitionable stream)
}

// quantize one value, bit-exact vs JAX:
//   r = bitcast((bits>>9)|0x3f800000) - 1
//   temp = floor(v*inv_sigma + r) * sigma   (v*inv_sigma exact pow-2 -> fma ok)
//   clip(temp, tmin, tmax)                  (fmin(fmax) -> v_med3_f32)
__device__ __forceinline__ float qround(float v, uint32_t bits, float sigma,
                                        float inv_sigma, float tmin, float tmax) {
  float r = __uint_as_float((bits >> 9) | 0x3f800000u) - 1.0f;
  float t = floorf(__builtin_fmaf(v, inv_sigma, r)) * sigma;
  return fminf(fmaxf(t, tmin), tmax);
}

// ---------------------------------------------------------------------------
// Kernel A: overflow/underflow counts. Grid-stride, 2048 wgs fully resident.
// Wave-level ballots (4 v_cmp/elem) + SALU popcount; lane 0 of each wave
// accumulates (lane 0 has the smallest i in the wave -> exits the loop last,
// so it is active in every iteration any lane is active).
// Conditional atomic: counts are 0 for sane data -> zero atomics issued.
// ---------------------------------------------------------------------------
__global__ __launch_bounds__(256) void count_kernel(
    const float4* __restrict__ x4, const float* __restrict__ x,
    long long n4, long long n, unsigned int* __restrict__ counts,
    float tmax, float tmin, float htmax, float htmin) {
  long long idx = (long long)blockIdx.x * 256 + threadIdx.x;
  long long stride = (long long)gridDim.x * 256;
  unsigned int over = 0, under = 0;
  for (long long i = idx; i < n4; i += stride) {
    float4 v = x4[i];
    over  += __popcll(__ballot(v.x > tmax))  + __popcll(__ballot(v.x < tmin))
           + __popcll(__ballot(v.y > tmax))  + __popcll(__ballot(v.y < tmin))
           + __popcll(__ballot(v.z > tmax))  + __popcll(__ballot(v.z < tmin))
           + __popcll(__ballot(v.w > tmax))  + __popcll(__ballot(v.w < tmin));
    under += __popcll(__ballot(v.x > htmax)) + __popcll(__ballot(v.x < htmin))
           + __popcll(__ballot(v.y > htmax)) + __popcll(__ballot(v.y < htmin))
           + __popcll(__ballot(v.z > htmax)) + __popcll(__ballot(v.z < htmin))
           + __popcll(__ballot(v.w > htmax)) + __popcll(__ballot(v.w < htmin));
  }
  if ((threadIdx.x & 63) == 0) {
    if (over)  atomicAdd(&counts[0], over);
    if (under) atomicAdd(&counts[1], under);
  }
  // generic scalar tail (n % 4 != 0) -- never taken for n = 2^27
  if (idx == 0 && (n & 3)) {
    unsigned int o2 = 0, u2 = 0;
    for (long long j = n4 << 2; j < n; ++j) {
      float v = x[j];
      o2 += (v > tmax)  + (v < tmin);
      u2 += (v > htmax) + (v < htmin);
    }
    if (o2) atomicAdd(&counts[0], o2);
    if (u2) atomicAdd(&counts[1], u2);
  }
}

// ---------------------------------------------------------------------------
// Kernel B: sigma from counts (uniform -> SALU), then stochastic-round.
// Grid-stride DESCENDING: count_kernel finished by streaming the tail of
// each access stripe, so the L3 (256 MiB) holds the high-i portion; starting
// quant at each thread's highest i turns the first ~256 MB of re-reads into
// L3 hits. Nontemporal store keeps the write stream from evicting x.
// ---------------------------------------------------------------------------
__global__ __launch_bounds__(256) void quant_kernel(
    const float4* __restrict__ x4, floatx4* __restrict__ o4,
    const float* __restrict__ x, float* __restrict__ out,
    long long n4, long long n, const unsigned int* __restrict__ counts,
    float inv_n, uint32_t k0, uint32_t k1) {
  const uint32_t ks2 = k0 ^ k1 ^ 0x1BD11BDAu;   // uniform -> SALU
  float overflow  = (float)counts[0] * inv_n;    // exact: inv_n = 2^-27
  float underflow = (float)counts[1] * inv_n;
  // sigma = where(over > .01, 2s, where(under < .01, s/2, s)), s = 0.25
  float sigma = (overflow > 0.01f) ? 0.5f
              : ((underflow < 0.01f) ? 0.125f : 0.25f);
  float tmax = sigma * 128.0f - sigma;
  float tmin = sigma * -128.0f;
  float inv_sigma = 1.0f / sigma;                // exact pow-2

  long long idx = (long long)blockIdx.x * 256 + threadIdx.x;
  long long stride = (long long)gridDim.x * 256;
  if (idx < n4) {
    // highest index this thread owns; iterate descending to idx
    long long i = idx + ((n4 - 1 - idx) / stride) * stride;
    for (; i >= idx; i -= stride) {
      float4 v = x4[i];
      uint32_t s = ((uint32_t)i << 2) + k1;      // ctr + k1, one v_lshl_add
      uint32_t b0 = tf_bits(s + 0u, k0, k1, ks2);
      uint32_t b1 = tf_bits(s + 1u, k0, k1, ks2);
      uint32_t b2 = tf_bits(s + 2u, k0, k1, ks2);
      uint32_t b3 = tf_bits(s + 3u, k0, k1, ks2);
      floatx4 r;
      r.x = qround(v.x, b0, sigma, inv_sigma, tmin, tmax);
      r.y = qround(v.y, b1, sigma, inv_sigma, tmin, tmax);
      r.z = qround(v.z, b2, sigma, inv_sigma, tmin, tmax);
      r.w = qround(v.w, b3, sigma, inv_sigma, tmin, tmax);
      __builtin_nontemporal_store(r, &o4[i]);
    }
  }
  // generic scalar tail -- never taken for n = 2^27
  if (idx == 0 && (n & 3)) {
    for (long long j = n4 << 2; j < n; ++j) {
      uint32_t b = tf_bits((uint32_t)j + k1, k0, k1, ks2);
      out[j] = qround(x[j], b, sigma, inv_sigma, tmin, tmax);
    }
  }
}

extern "C" void kernel_launch(void* const* d_in, const int* in_sizes, int n_in,
                              void* d_out, int out_size, void* d_ws, size_t ws_size,
                              hipStream_t stream) {
  const float* x = (const float*)d_in[0];
  float* out = (float*)d_out;
  long long n = (long long)in_sizes[0];   // 134217728 = 2^27 elements

  unsigned int* counts = (unsigned int*)d_ws;
  (void)hipMemsetAsync(counts, 0, 2 * sizeof(unsigned int), stream);

  // rkey = fold_in(key(42), 0) = threefry((0,42), (0,0)) -- config-independent
  uint32_t k0, k1;
  threefry2x32_host(0u, 42u, 0u, 0u, k0, k1);

  const float sigma0 = 0.25f;
  const float tmax0 = sigma0 * 128.0f - sigma0;   // 31.75
  const float tmin0 = -sigma0 * 128.0f;           // -32
  const float htmax0 = 0.5f * tmax0;              // 15.875
  const float htmin0 = 0.5f * tmin0;              // -16

  long long n4 = n >> 2;
  long long grid = (n4 + 255) / 256;
  if (grid < 1) grid = 1;
  if (grid > 2048) grid = 2048;   // 8 wg/CU, fully resident, grid-stride

  count_kernel<<<(dim3)(unsigned)grid, 256, 0, stream>>>(
      (const float4*)x, x, n4, n, counts, tmax0, tmin0, htmax0, htmin0);

  float inv_n = 1.0f / (float)n;
  quant_kernel<<<(dim3)(unsigned)grid, 256, 0, stream>>>(
      (const float4*)x, (floatx4*)out, x, out, n4, n, counts, inv_n, k0, k1);
}

// Round 4
// 878.260 us; speedup vs baseline: 1.2243x; 1.2243x over previous
//
#include <hip/hip_runtime.h>
#include <stdint.h>

// native 4-float vector (same layout as float4), valid for vector builtins
typedef float floatx4 __attribute__((ext_vector_type(4)));

// ---------------------------------------------------------------------------
// Host copy of exact JAX Threefry-2x32 (jax/_src/prng.py; Random123 constants)
// used only to derive rkey = fold_in(key(42), 0) on the host.
// ---------------------------------------------------------------------------
static inline void threefry2x32_host(uint32_t k0, uint32_t k1,
                                     uint32_t x0, uint32_t x1,
                                     uint32_t& o0, uint32_t& o1) {
  const uint32_t ks2 = k0 ^ k1 ^ 0x1BD11BDAu;
#define TF_ROUND(r) { x0 += x1; x1 = (x1 << (r)) | (x1 >> (32 - (r))); x1 ^= x0; }
  x0 += k0; x1 += k1;
  TF_ROUND(13) TF_ROUND(15) TF_ROUND(26) TF_ROUND(6)
  x0 += k1;  x1 += ks2 + 1u;
  TF_ROUND(17) TF_ROUND(29) TF_ROUND(16) TF_ROUND(24)
  x0 += ks2; x1 += k0 + 2u;
  TF_ROUND(13) TF_ROUND(15) TF_ROUND(26) TF_ROUND(6)
  x0 += k0;  x1 += k1 + 3u;
  TF_ROUND(17) TF_ROUND(29) TF_ROUND(16) TF_ROUND(24)
  x0 += k1;  x1 += ks2 + 4u;
  TF_ROUND(13) TF_ROUND(15) TF_ROUND(26) TF_ROUND(6)
  x0 += ks2; x1 += k0 + 5u;
#undef TF_ROUND
  o0 = x0; o1 = x1;
}

// ---------------------------------------------------------------------------
// Device: jax partitionable 32-bit draw for counter ctr (< 2^32).
// Caller passes x1 = ctr + k1 (initial key add strength-reduced); x0 = k0.
// Rotates via __builtin_rotateleft32 -> v_alignbit_b32.
// 20*(add,alignbit,xor) + 10 injection adds + final xor ~= 71 VALU ops.
// ---------------------------------------------------------------------------
__device__ __forceinline__ uint32_t tf_bits(uint32_t x1, uint32_t k0,
                                            uint32_t k1, uint32_t ks2) {
  uint32_t x0 = k0;
#define R4(a,b,c,d)                                              \
  x0 += x1; x1 = __builtin_rotateleft32(x1, a); x1 ^= x0;        \
  x0 += x1; x1 = __builtin_rotateleft32(x1, b); x1 ^= x0;        \
  x0 += x1; x1 = __builtin_rotateleft32(x1, c); x1 ^= x0;        \
  x0 += x1; x1 = __builtin_rotateleft32(x1, d); x1 ^= x0;
  R4(13, 15, 26, 6)
  x0 += k1;  x1 += ks2 + 1u;
  R4(17, 29, 16, 24)
  x0 += ks2; x1 += k0 + 2u;
  R4(13, 15, 26, 6)
  x0 += k0;  x1 += k1 + 3u;
  R4(17, 29, 16, 24)
  x0 += k1;  x1 += ks2 + 4u;
  R4(13, 15, 26, 6)
  x0 += ks2; x1 += k0 + 5u;
#undef R4
  return x0 ^ x1;  // bits = o0 ^ o1 (partitionable stream)
}

// quantize one value, bit-exact vs JAX:
//   r = bitcast((bits>>9)|0x3f800000) - 1
//   temp = floor(v*inv_sigma + r) * sigma   (v*inv_sigma exact pow-2 -> fma ok)
//   clip(temp, tmin, tmax)
__device__ __forceinline__ float qround(float v, uint32_t bits, float sigma,
                                        float inv_sigma, float tmin, float tmax) {
  float r = __uint_as_float((bits >> 9) | 0x3f800000u) - 1.0f;
  float t = floorf(__builtin_fmaf(v, inv_sigma, r)) * sigma;
  return fminf(fmaxf(t, tmin), tmax);
}

// ---------------------------------------------------------------------------
// Fused kernel: ONE pass over x. Computes overflow/underflow counts at the
// sigma0 thresholds AND the quantized output speculatively with
// sigma_spec = 0.125 (the value the reference selects whenever underflow<1%,
// i.e. any well-scaled input). resolve_kernel validates the guess from the
// global counts; fixup_kernel repairs on mispredict (correct for ANY input).
// Fast path deletes the entire separate count pass (~170 us).
// Exact grid, 1 float4/thread (fastest observed shape), ascending, plain
// stores. Counting via ballot -> SALU popcount: only 16 v_cmp on the VALU
// issue port; lane-0 conditional atomic (zero atomics for sane data).
// ---------------------------------------------------------------------------
__global__ __launch_bounds__(256) void fused_kernel(
    const float4* __restrict__ x4, floatx4* __restrict__ o4,
    const float* __restrict__ x, float* __restrict__ out,
    long long n4, long long n, unsigned int* __restrict__ counts,
    uint32_t k0, uint32_t k1) {
  const uint32_t ks2 = k0 ^ k1 ^ 0x1BD11BDAu;   // uniform -> SALU
  // speculative quant params (sigma = 0.125)
  const float sigma = 0.125f, inv_sigma = 8.0f;
  const float tmax = 15.875f, tmin = -16.0f;
  // sigma0 = 0.25 count thresholds (reference constants)
  const float ctmax = 31.75f, ctmin = -32.0f;
  const float chtmax = 15.875f, chtmin = -16.0f;

  long long i = (long long)blockIdx.x * 256 + threadIdx.x;
  unsigned int over = 0, under = 0;
  if (i < n4) {
    float4 v = x4[i];
    over  = __popcll(__ballot(v.x > ctmax))  + __popcll(__ballot(v.x < ctmin))
          + __popcll(__ballot(v.y > ctmax))  + __popcll(__ballot(v.y < ctmin))
          + __popcll(__ballot(v.z > ctmax))  + __popcll(__ballot(v.z < ctmin))
          + __popcll(__ballot(v.w > ctmax))  + __popcll(__ballot(v.w < ctmin));
    under = __popcll(__ballot(v.x > chtmax)) + __popcll(__ballot(v.x < chtmin))
          + __popcll(__ballot(v.y > chtmax)) + __popcll(__ballot(v.y < chtmin))
          + __popcll(__ballot(v.z > chtmax)) + __popcll(__ballot(v.z < chtmin))
          + __popcll(__ballot(v.w > chtmax)) + __popcll(__ballot(v.w < chtmin));
    uint32_t s = ((uint32_t)i << 2) + k1;        // ctr + k1, one v_lshl_add
    uint32_t b0 = tf_bits(s + 0u, k0, k1, ks2);
    uint32_t b1 = tf_bits(s + 1u, k0, k1, ks2);
    uint32_t b2 = tf_bits(s + 2u, k0, k1, ks2);
    uint32_t b3 = tf_bits(s + 3u, k0, k1, ks2);
    floatx4 r;
    r.x = qround(v.x, b0, sigma, inv_sigma, tmin, tmax);
    r.y = qround(v.y, b1, sigma, inv_sigma, tmin, tmax);
    r.z = qround(v.z, b2, sigma, inv_sigma, tmin, tmax);
    r.w = qround(v.w, b3, sigma, inv_sigma, tmin, tmax);
    o4[i] = r;
  }
  // lane 0 active iff any lane of the wave was active (smallest i in wave)
  if ((threadIdx.x & 63) == 0) {
    if (over)  atomicAdd(&counts[0], over);
    if (under) atomicAdd(&counts[1], under);
  }
  // generic scalar tail (n % 4 != 0) -- dead for n = 2^27
  if (i == 0 && (n & 3)) {
    unsigned int o2 = 0, u2 = 0;
    for (long long j = n4 << 2; j < n; ++j) {
      float v = x[j];
      o2 += (v > ctmax)  + (v < ctmin);
      u2 += (v > chtmax) + (v < chtmin);
      uint32_t b = tf_bits((uint32_t)j + k1, k0, k1, ks2);
      out[j] = qround(v, b, sigma, inv_sigma, tmin, tmax);
    }
    if (o2) atomicAdd(&counts[0], o2);
    if (u2) atomicAdd(&counts[1], u2);
  }
}

// ---------------------------------------------------------------------------
// Resolve: derive true sigma from global counts; flag mispredict; publish
// quant params for the fixup pass. 1 thread.
// ---------------------------------------------------------------------------
__global__ void resolve_kernel(const unsigned int* __restrict__ counts,
                               unsigned int* __restrict__ flag,
                               float* __restrict__ params, float inv_n) {
  float overflow  = (float)counts[0] * inv_n;    // exact: inv_n = 2^-27
  float underflow = (float)counts[1] * inv_n;
  // sigma = where(over > .01, 2s, where(under < .01, s/2, s)), s = 0.25
  float sigma = (overflow > 0.01f) ? 0.5f
              : ((underflow < 0.01f) ? 0.125f : 0.25f);
  flag[0] = (sigma != 0.125f) ? 1u : 0u;         // speculation check
  params[0] = sigma;
  params[1] = 1.0f / sigma;                      // exact pow-2
  params[2] = sigma * -128.0f;                   // tmin
  params[3] = sigma * 128.0f - sigma;            // tmax
}

// ---------------------------------------------------------------------------
// Fixup: on mispredict, recompute the whole output with the true sigma.
// Fast path: flag == 0 -> every wg exits after one scalar load (~few us).
// ---------------------------------------------------------------------------
__global__ __launch_bounds__(256) void fixup_kernel(
    const float4* __restrict__ x4, floatx4* __restrict__ o4,
    const float* __restrict__ x, float* __restrict__ out,
    long long n4, long long n, const unsigned int* __restrict__ flag,
    const float* __restrict__ params, uint32_t k0, uint32_t k1) {
  if (flag[0] == 0u) return;                     // speculation held
  const uint32_t ks2 = k0 ^ k1 ^ 0x1BD11BDAu;
  float sigma = params[0], inv_sigma = params[1];
  float tmin = params[2], tmax = params[3];
  long long idx = (long long)blockIdx.x * 256 + threadIdx.x;
  long long stride = (long long)gridDim.x * 256;
  for (long long i = idx; i < n4; i += stride) {
    float4 v = x4[i];
    uint32_t s = ((uint32_t)i << 2) + k1;
    uint32_t b0 = tf_bits(s + 0u, k0, k1, ks2);
    uint32_t b1 = tf_bits(s + 1u, k0, k1, ks2);
    uint32_t b2 = tf_bits(s + 2u, k0, k1, ks2);
    uint32_t b3 = tf_bits(s + 3u, k0, k1, ks2);
    floatx4 r;
    r.x = qround(v.x, b0, sigma, inv_sigma, tmin, tmax);
    r.y = qround(v.y, b1, sigma, inv_sigma, tmin, tmax);
    r.z = qround(v.z, b2, sigma, inv_sigma, tmin, tmax);
    r.w = qround(v.w, b3, sigma, inv_sigma, tmin, tmax);
    o4[i] = r;
  }
  if (idx == 0 && (n & 3)) {
    for (long long j = n4 << 2; j < n; ++j) {
      uint32_t b = tf_bits((uint32_t)j + k1, k0, k1, ks2);
      out[j] = qround(x[j], b, sigma, inv_sigma, tmin, tmax);
    }
  }
}

extern "C" void kernel_launch(void* const* d_in, const int* in_sizes, int n_in,
                              void* d_out, int out_size, void* d_ws, size_t ws_size,
                              hipStream_t stream) {
  const float* x = (const float*)d_in[0];
  float* out = (float*)d_out;
  long long n = (long long)in_sizes[0];   // 134217728 = 2^27 elements

  // workspace: [0..1] counts, [2] flag, [4..7] params (floats)
  unsigned int* counts = (unsigned int*)d_ws;
  unsigned int* flag = counts + 2;
  float* params = (float*)(counts + 4);
  (void)hipMemsetAsync(counts, 0, 2 * sizeof(unsigned int), stream);

  // rkey = fold_in(key(42), 0) = threefry((0,42), (0,0)) -- config-independent
  uint32_t k0, k1;
  threefry2x32_host(0u, 42u, 0u, 0u, k0, k1);

  long long n4 = n >> 2;
  long long grid = (n4 + 255) / 256;
  if (grid < 1) grid = 1;                 // thread 0 must exist (tail)

  fused_kernel<<<(dim3)(unsigned)grid, 256, 0, stream>>>(
      (const float4*)x, (floatx4*)out, x, out, n4, n, counts, k0, k1);

  float inv_n = 1.0f / (float)n;
  resolve_kernel<<<1, 1, 0, stream>>>(counts, flag, params, inv_n);

  long long gridf = grid;
  if (gridf > 2048) gridf = 2048;         // early-exit cheap; loop if mispredict
  fixup_kernel<<<(dim3)(unsigned)gridf, 256, 0, stream>>>(
      (const float4*)x, (floatx4*)out, x, out, n4, n, flag, params, k0, k1);
}